// Round 2
// 946.716 us; speedup vs baseline: 1.0745x; 1.0745x over previous
//
#include <hip/hip_runtime.h>
#include <math.h>

#define CIN    128
#define HID    128
#define HDIM   64
#define WDIM   64
#define HW     4096
#define KTOT   640      // 256 x-part (2 taps x 128c) + 384 h-part (3 taps x 128c)
#define NTOT   512      // 4 gates x 128 hid
#define LDSROW 136      // shorts per A-row: 128 + 8 pad (272 B, 16B-aligned)
#define NBATCH 16
#define BFRAG  (4 * 20 * 64 * 8)   // 40960 shorts = 80 KiB per he-slice
#define HBUF   (NBATCH * WDIM * HID)   // shorts per h parity buffer

typedef short short8 __attribute__((ext_vector_type(8)));
typedef float f32x4  __attribute__((ext_vector_type(4)));
typedef unsigned int u32x4 __attribute__((ext_vector_type(4)));

__device__ __forceinline__ unsigned short f2bf(float f) {
    union { float f; unsigned int u; } v; v.f = f;
    unsigned int r = v.u + 0x7fffu + ((v.u >> 16) & 1u);   // RNE
    return (unsigned short)(r >> 16);
}
__device__ __forceinline__ float sigm(float x)  { return 1.0f / (1.0f + __expf(-x)); }
__device__ __forceinline__ float tanhft(float x){ return 2.0f / (1.0f + __expf(-2.0f * x)) - 1.0f; }

// ---------------------------------------------------------------------------
// Pack: Wpk in FRAGMENT order so the persistent kernel can bulk-copy its slice
// to LDS and read B-frags as linear (conflict-free) ds_read_b128:
//   idx = (((he*4+g)*20 + ks)*64 + lane)*8 + j
//   n = g*128 + he*16 + (lane&15),  k = ks*32 + (lane>>4)*8 + j
//   k<256: x-part, W_is tap t=k>>7 (causal taps 0,1); else h-part W_ss taps 0..2
// Also: bias_p[n] = b_is+b_ss, and zero the 16x64 barrier counters.
// ---------------------------------------------------------------------------
__global__ void pack_kernel(const float* __restrict__ W_is,
                            const float* __restrict__ b_is,
                            const float* __restrict__ W_ss,
                            const float* __restrict__ b_ss,
                            unsigned short* __restrict__ Wpk,
                            float* __restrict__ bias_p,
                            unsigned int* __restrict__ bar) {
    int idx = blockIdx.x * blockDim.x + threadIdx.x;
    if (idx < NTOT * KTOT) {
        int j    = idx & 7;
        int lane = (idx >> 3) & 63;
        int t2   = idx >> 9;            // (he*4+g)*20 + ks
        int ks   = t2 % 20;
        int gg   = t2 / 20;             // he*4 + g
        int g    = gg & 3;
        int he   = gg >> 2;
        int n = g * 128 + he * 16 + (lane & 15);
        int k = ks * 32 + (lane >> 4) * 8 + j;
        float v;
        if (k < 256) { int t = k >> 7, c = k & 127; v = W_is[((size_t)n * CIN + c) * 3 + t]; }
        else { int kk = k - 256; int t = kk >> 7, c = kk & 127; v = W_ss[((size_t)n * HID + c) * 3 + t]; }
        Wpk[idx] = f2bf(v);
    }
    if (idx < NTOT) bias_p[idx] = b_is[idx] + b_ss[idx];
    if (idx < NBATCH * HDIM) bar[idx] = 0;
}

// ---------------------------------------------------------------------------
// Persistent LSTM kernel: grid 128 = (b 0..15) x (he 0..7), 256 thr, 1 blk/CU.
//  - B-slice (80 KiB) LDS-resident for all 64 rows (frag order, linear reads)
//  - c-state in registers for all 64 rows
//  - x row r+1 prefetched to double-buffered LDS during row r
//  - h exchanged via bf16 global h_bf[parity][b][w][c] (PING-PONG by row
//    parity: bar[b][r]==8 implies all partners finished READING h(r-1)+... and
//    writing h(r); parity r&1 is only rewritten at row r+2, gated on
//    bar[b][r+1] which implies all reads of parity r&1 are done) -> race-free
//  - x-part GEMM of row r+1 issued after arrive, before next spin (hides skew)
// ---------------------------------------------------------------------------
#define GEMM_X(BUF)                                                            \
    {                                                                          \
        _Pragma("unroll")                                                      \
        for (int ks = 0; ks < 8; ++ks) {                                       \
            const int t = ks >> 2, c0 = (ks & 3) * 32;                         \
            short8 a = *(const short8*)&(BUF)[(wv * 16 + t) * LDSROW + c0 + a_off]; \
            _Pragma("unroll")                                                  \
            for (int g = 0; g < 4; ++g) {                                      \
                short8 bq = *(const short8*)&lds_b[((g * 20 + ks) * 64 + lane) * 8]; \
                acc[g] = __builtin_amdgcn_mfma_f32_16x16x32_bf16(a, bq, acc[g], 0, 0, 0); \
            }                                                                  \
        }                                                                      \
    }

#define GEMM_H                                                                 \
    {                                                                          \
        _Pragma("unroll")                                                      \
        for (int ks = 0; ks < 12; ++ks) {                                      \
            const int t = ks >> 2, c0 = (ks & 3) * 32;                         \
            short8 a = *(const short8*)&lds_h[(wv * 16 + t) * LDSROW + c0 + a_off]; \
            _Pragma("unroll")                                                  \
            for (int g = 0; g < 4; ++g) {                                      \
                short8 bq = *(const short8*)&lds_b[((g * 20 + 8 + ks) * 64 + lane) * 8]; \
                acc[g] = __builtin_amdgcn_mfma_f32_16x16x32_bf16(a, bq, acc[g], 0, 0, 0); \
            }                                                                  \
        }                                                                      \
    }

#define STAGE_X(ROW, BUF)                                                      \
    {                                                                          \
        const float* xrow = x + (size_t)b * (CIN * HW) + (size_t)(ROW) * WDIM; \
        _Pragma("unroll")                                                      \
        for (int p = 0; p < 16; ++p) {                                         \
            int flat = p * 256 + tid;                                          \
            int w  = flat & 63;                                                \
            int cp = flat >> 6;                                                \
            float v0 = xrow[(2 * cp    ) * HW + w];                            \
            float v1 = xrow[(2 * cp + 1) * HW + w];                            \
            ((unsigned*)(BUF))[(w + 1) * 68 + cp] =                            \
                (unsigned)f2bf(v0) | ((unsigned)f2bf(v1) << 16);               \
        }                                                                      \
    }

#define STAGE_H(HB)                                                            \
    {                                                                          \
        const u32x4* hsrc = (const u32x4*)((HB) + (size_t)b * (WDIM * HID));   \
        _Pragma("unroll")                                                      \
        for (int p = 0; p < 4; ++p) {                                          \
            int chunk = p * 256 + tid;                                         \
            int w  = chunk >> 4;                                               \
            int co = chunk & 15;                                               \
            *(u32x4*)&lds_h[(w + 1) * LDSROW + co * 8] = hsrc[chunk];          \
        }                                                                      \
    }

__global__ __launch_bounds__(256, 1) void lstm_kernel(
        const float* __restrict__ x,
        const unsigned short* __restrict__ Wpk,
        const float* __restrict__ bias_p,
        unsigned short* h_bf,
        unsigned int* bar,
        float* __restrict__ out) {
    __shared__ __align__(16) unsigned short lds_b[BFRAG];          // 80 KiB
    __shared__ __align__(16) unsigned short lds_x[2][66 * LDSROW]; // 2 x 17.5 KiB
    __shared__ __align__(16) unsigned short lds_h[66 * LDSROW];    // 17.5 KiB

    const int tid  = threadIdx.x;
    const int b    = blockIdx.x & 15;
    const int he   = blockIdx.x >> 4;      // h-sixteenth (16 channels)
    const int wv   = tid >> 6;             // wave = m-tile (16 w)
    const int lane = tid & 63;
    const int quad = lane >> 4;
    const int l15  = lane & 15;

    // ---- prologue: B-slice -> LDS (contiguous, once) ----
    {
        const u32x4* src = (const u32x4*)(Wpk + (size_t)he * BFRAG);
        u32x4* dst = (u32x4*)lds_b;
#pragma unroll
        for (int p = 0; p < 20; ++p) dst[p * 256 + tid] = src[p * 256 + tid];
    }
    // halo rows (w_eff = -1 and 64) stay zero for the whole kernel
    if (tid < 68) {
        ((unsigned*)lds_x[0])[tid] = 0;
        ((unsigned*)lds_x[1])[tid] = 0;
        ((unsigned*)lds_h)[tid] = 0;
        ((unsigned*)lds_h)[65 * 68 + tid] = 0;
    }
    STAGE_X(0, lds_x[0]);
    __syncthreads();

    const int hch = he * 16 + l15;
    const float bi  = bias_p[      hch];
    const float bf_ = bias_p[128 + hch];
    const float bo  = bias_p[256 + hch];
    const float bg  = bias_p[384 + hch];
    const int a_off = l15 * LDSROW + quad * 8;

    f32x4 acc[4];
#pragma unroll
    for (int g = 0; g < 4; ++g) acc[g] = (f32x4){0.f, 0.f, 0.f, 0.f};
    f32x4 creg = (f32x4){0.f, 0.f, 0.f, 0.f};

    GEMM_X(lds_x[0]);                       // x-part of row 0

    for (int r = 0; r < HDIM; ++r) {
        if (r < HDIM - 1) STAGE_X(r + 1, lds_x[(r + 1) & 1]);   // prefetch next x row

        if (r > 0) {
            if (tid == 0) {                 // wait for all 8 partners' h(r-1)
                while (atomicAdd(&bar[(b << 6) + (r - 1)], 0u) < 8u) { }
            }
            __syncthreads();
            __threadfence();                // acquire: see partners' h_bf writes
            STAGE_H(h_bf + (size_t)((r - 1) & 1) * HBUF);
            __syncthreads();
            GEMM_H;                         // h-part of row r into acc
        }

        // ---- LSTM epilogue: all 4 gates lane-local; c stays in registers ----
        {
            const int w0 = wv * 16 + quad * 4;
            f32x4 hv;
#pragma unroll
            for (int e = 0; e < 4; ++e) {
                float zi = acc[0][e] + bi;
                float zf = acc[1][e] + bf_;
                float zo = acc[2][e] + bo;
                float zg = acc[3][e] + bg;
                float ig = sigm(zi), fg = sigm(zf), og = sigm(zo);
                float gg = tanhft(zg);
                float cn = fg * creg[e] + ig * gg;
                creg[e] = cn;
                hv[e]   = og * tanhft(cn);
            }
            *(f32x4*)&out[(((size_t)b * HID + hch) * HDIM + r) * WDIM + w0] = hv;
            unsigned short* hb = h_bf + (size_t)(r & 1) * HBUF
                               + ((size_t)b * WDIM + w0) * HID + hch;
#pragma unroll
            for (int e = 0; e < 4; ++e) hb[e * HID] = f2bf(hv[e]);
        }

        if (r < HDIM - 1) {
            __syncthreads();                // drains all waves' stores (vmcnt 0)
            if (tid == 0) {
                __threadfence();            // release h_bf to agent scope
                atomicAdd(&bar[(b << 6) + r], 1u);
            }
#pragma unroll
            for (int g = 0; g < 4; ++g) acc[g] = (f32x4){0.f, 0.f, 0.f, 0.f};
            GEMM_X(lds_x[(r + 1) & 1]);    // x-part of row r+1: hides barrier skew
        }
    }
}

extern "C" void kernel_launch(void* const* d_in, const int* in_sizes, int n_in,
                              void* d_out, int out_size, void* d_ws, size_t ws_size,
                              hipStream_t stream) {
    const float* x    = (const float*)d_in[0];
    const float* W_is = (const float*)d_in[1];
    const float* b_is = (const float*)d_in[2];
    const float* W_ss = (const float*)d_in[3];
    const float* b_ss = (const float*)d_in[4];
    float* out = (float*)d_out;

    // ws: h_bf bf16[2][16*64*128] | Wpk bf16[512*640 frag-order] | bias f32[512] | bar u32[16*64]
    unsigned short* h_bf   = (unsigned short*)d_ws;                      // 524288 B
    unsigned short* Wpk    = (unsigned short*)((char*)d_ws + 524288);    // 655360 B
    float*          bias_p = (float*)((char*)d_ws + 1179648);            //   2048 B
    unsigned int*   bar    = (unsigned int*)((char*)d_ws + 1181696);     //   4096 B

    pack_kernel<<<(NTOT * KTOT + 255) / 256, 256, 0, stream>>>(
        W_is, b_is, W_ss, b_ss, Wpk, bias_p, bar);
    lstm_kernel<<<128, 256, 0, stream>>>(x, Wpk, bias_p, h_bf, bar, out);
}

// Round 3
// 526.888 us; speedup vs baseline: 1.9306x; 1.7968x over previous
//
#include <hip/hip_runtime.h>
#include <math.h>

#define CIN    128
#define HID    128
#define HDIM   64
#define WDIM   64
#define HW     4096
#define KTOT   640      // 256 x-part (2 taps x 128c) + 384 h-part (3 taps x 128c)
#define NTOT   512      // 4 gates x 128 hid
#define LDSROW 136      // shorts per A-row: 128 + 8 pad (272 B, 16B-aligned)
#define NBATCH 16
#define BFRAG  (4 * 20 * 64 * 8)   // 40960 shorts = 80 KiB per he-slice
#define HBUF   (NBATCH * WDIM * HID)   // shorts per h parity buffer

typedef short short8 __attribute__((ext_vector_type(8)));
typedef float f32x4  __attribute__((ext_vector_type(4)));
typedef unsigned int u32x4 __attribute__((ext_vector_type(4)));

#define ALOAD(p)     __hip_atomic_load((p), __ATOMIC_RELAXED, __HIP_MEMORY_SCOPE_AGENT)
#define ASTORE(p, v) __hip_atomic_store((p), (v), __ATOMIC_RELAXED, __HIP_MEMORY_SCOPE_AGENT)

__device__ __forceinline__ unsigned short f2bf(float f) {
    union { float f; unsigned int u; } v; v.f = f;
    unsigned int r = v.u + 0x7fffu + ((v.u >> 16) & 1u);   // RNE
    return (unsigned short)(r >> 16);
}
__device__ __forceinline__ float sigm(float x)  { return 1.0f / (1.0f + __expf(-x)); }
__device__ __forceinline__ float tanhft(float x){ return 2.0f / (1.0f + __expf(-2.0f * x)) - 1.0f; }

// ---------------------------------------------------------------------------
// Pack: Wpk in FRAGMENT order so the persistent kernel can bulk-copy its slice
// to LDS and read B-frags as linear (conflict-free) ds_read_b128:
//   idx = (((he*4+g)*20 + ks)*64 + lane)*8 + j
//   n = g*128 + he*16 + (lane&15),  k = ks*32 + (lane>>4)*8 + j
//   k<256: x-part, W_is tap t=k>>7 (causal taps 0,1); else h-part W_ss taps 0..2
// Also: bias_p[n] = b_is+b_ss, and zero the 16x64 barrier counters.
// ---------------------------------------------------------------------------
__global__ void pack_kernel(const float* __restrict__ W_is,
                            const float* __restrict__ b_is,
                            const float* __restrict__ W_ss,
                            const float* __restrict__ b_ss,
                            unsigned short* __restrict__ Wpk,
                            float* __restrict__ bias_p,
                            unsigned int* __restrict__ bar) {
    int idx = blockIdx.x * blockDim.x + threadIdx.x;
    if (idx < NTOT * KTOT) {
        int j    = idx & 7;
        int lane = (idx >> 3) & 63;
        int t2   = idx >> 9;            // (he*4+g)*20 + ks
        int ks   = t2 % 20;
        int gg   = t2 / 20;             // he*4 + g
        int g    = gg & 3;
        int he   = gg >> 2;
        int n = g * 128 + he * 16 + (lane & 15);
        int k = ks * 32 + (lane >> 4) * 8 + j;
        float v;
        if (k < 256) { int t = k >> 7, c = k & 127; v = W_is[((size_t)n * CIN + c) * 3 + t]; }
        else { int kk = k - 256; int t = kk >> 7, c = kk & 127; v = W_ss[((size_t)n * HID + c) * 3 + t]; }
        Wpk[idx] = f2bf(v);
    }
    if (idx < NTOT) bias_p[idx] = b_is[idx] + b_ss[idx];
    if (idx < NBATCH * HDIM) bar[idx] = 0;
}

// ---------------------------------------------------------------------------
// Persistent LSTM kernel: grid 128 = (b 0..15) x (he 0..7), 256 thr, 1 blk/CU.
//  - B-slice (80 KiB) LDS-resident for all 64 rows (frag order, linear reads)
//  - c-state in registers for all 64 rows
//  - x row r+1 prefetched to double-buffered LDS during row r
//  - h exchanged via bf16 global h_bf[parity][b][w][c], accessed ONLY through
//    agent-scope RELAXED atomics (coherent at device scope, NO cache fences ->
//    no L2 writeback/invalidate per row). Ordering: __syncthreads() drains
//    each thread's vmcnt (stores performed at coherence point) before arrive.
//  - bar poll: all threads, plain coherent atomic LOAD (no RMW) -> no tid0
//    broadcast sync needed; parity ping-pong makes overwrite race-free
//    (parity r&1 rewritten at row r+2, gated on bar[r+1] which implies all
//    reads of parity r&1 completed).
//  - x-part GEMM of row r+1 issued after arrive, before next poll (hides skew)
// ---------------------------------------------------------------------------
#define GEMM_X(BUF)                                                            \
    {                                                                          \
        _Pragma("unroll")                                                      \
        for (int ks = 0; ks < 8; ++ks) {                                       \
            const int t = ks >> 2, c0 = (ks & 3) * 32;                         \
            short8 a = *(const short8*)&(BUF)[(wv * 16 + t) * LDSROW + c0 + a_off]; \
            _Pragma("unroll")                                                  \
            for (int g = 0; g < 4; ++g) {                                      \
                short8 bq = *(const short8*)&lds_b[((g * 20 + ks) * 64 + lane) * 8]; \
                acc[g] = __builtin_amdgcn_mfma_f32_16x16x32_bf16(a, bq, acc[g], 0, 0, 0); \
            }                                                                  \
        }                                                                      \
    }

#define GEMM_H                                                                 \
    {                                                                          \
        _Pragma("unroll")                                                      \
        for (int ks = 0; ks < 12; ++ks) {                                      \
            const int t = ks >> 2, c0 = (ks & 3) * 32;                         \
            short8 a = *(const short8*)&lds_h[(wv * 16 + t) * LDSROW + c0 + a_off]; \
            _Pragma("unroll")                                                  \
            for (int g = 0; g < 4; ++g) {                                      \
                short8 bq = *(const short8*)&lds_b[((g * 20 + 8 + ks) * 64 + lane) * 8]; \
                acc[g] = __builtin_amdgcn_mfma_f32_16x16x32_bf16(a, bq, acc[g], 0, 0, 0); \
            }                                                                  \
        }                                                                      \
    }

#define STAGE_X(ROW, BUF)                                                      \
    {                                                                          \
        const float* xrow = x + (size_t)b * (CIN * HW) + (size_t)(ROW) * WDIM; \
        _Pragma("unroll")                                                      \
        for (int p = 0; p < 16; ++p) {                                         \
            int flat = p * 256 + tid;                                          \
            int w  = flat & 63;                                                \
            int cp = flat >> 6;                                                \
            float v0 = xrow[(2 * cp    ) * HW + w];                            \
            float v1 = xrow[(2 * cp + 1) * HW + w];                            \
            ((unsigned*)(BUF))[(w + 1) * 68 + cp] =                            \
                (unsigned)f2bf(v0) | ((unsigned)f2bf(v1) << 16);               \
        }                                                                      \
    }

// coherent (agent-scope relaxed) staged read of partner h: 16 x u32 per thread
#define STAGE_H(HB)                                                            \
    {                                                                          \
        const unsigned* hsrc = (const unsigned*)((HB) + (size_t)b * (WDIM * HID)); \
        _Pragma("unroll")                                                      \
        for (int p = 0; p < 16; ++p) {                                         \
            int flat = p * 256 + tid;                                          \
            int w  = flat >> 6;                                                \
            int co = flat & 63;                                                \
            ((unsigned*)lds_h)[(w + 1) * 68 + co] = ALOAD(&hsrc[flat]);        \
        }                                                                      \
    }

__global__ __launch_bounds__(256, 1) void lstm_kernel(
        const float* __restrict__ x,
        const unsigned short* __restrict__ Wpk,
        const float* __restrict__ bias_p,
        unsigned short* h_bf,
        unsigned int* bar,
        float* __restrict__ out) {
    __shared__ __align__(16) unsigned short lds_b[BFRAG];          // 80 KiB
    __shared__ __align__(16) unsigned short lds_x[2][66 * LDSROW]; // 2 x 17.5 KiB
    __shared__ __align__(16) unsigned short lds_h[66 * LDSROW];    // 17.5 KiB

    const int tid  = threadIdx.x;
    const int b    = blockIdx.x & 15;      // partners share blockIdx%8 -> same XCD (perf only)
    const int he   = blockIdx.x >> 4;      // h-sixteenth (16 channels)
    const int wv   = tid >> 6;             // wave = m-tile (16 w)
    const int lane = tid & 63;
    const int quad = lane >> 4;
    const int l15  = lane & 15;

    // ---- prologue: B-slice -> LDS (contiguous, once) ----
    {
        const u32x4* src = (const u32x4*)(Wpk + (size_t)he * BFRAG);
        u32x4* dst = (u32x4*)lds_b;
#pragma unroll
        for (int p = 0; p < 20; ++p) dst[p * 256 + tid] = src[p * 256 + tid];
    }
    // halo rows (w_eff = -1 and 64) stay zero for the whole kernel
    if (tid < 68) {
        ((unsigned*)lds_x[0])[tid] = 0;
        ((unsigned*)lds_x[1])[tid] = 0;
        ((unsigned*)lds_h)[tid] = 0;
        ((unsigned*)lds_h)[65 * 68 + tid] = 0;
    }
    STAGE_X(0, lds_x[0]);
    __syncthreads();

    const int hch = he * 16 + l15;
    const float bi  = bias_p[      hch];
    const float bf_ = bias_p[128 + hch];
    const float bo  = bias_p[256 + hch];
    const float bg  = bias_p[384 + hch];
    const int a_off = l15 * LDSROW + quad * 8;

    f32x4 acc[4];
#pragma unroll
    for (int g = 0; g < 4; ++g) acc[g] = (f32x4){0.f, 0.f, 0.f, 0.f};
    f32x4 creg = (f32x4){0.f, 0.f, 0.f, 0.f};

    GEMM_X(lds_x[0]);                       // x-part of row 0

    for (int r = 0; r < HDIM; ++r) {
        if (r < HDIM - 1) STAGE_X(r + 1, lds_x[(r + 1) & 1]);   // prefetch next x row

        if (r > 0) {
            // all threads poll (coherent load, no RMW, no broadcast sync)
            const unsigned* bp = &bar[(b << 6) + (r - 1)];
            while (ALOAD(bp) < 8u) { }
            STAGE_H(h_bf + (size_t)((r - 1) & 1) * HBUF);
            __syncthreads();                // lds_h ready for all waves
            GEMM_H;                         // h-part of row r into acc
        }

        // ---- LSTM epilogue: all 4 gates lane-local; c stays in registers ----
        {
            const int w0 = wv * 16 + quad * 4;
            f32x4 hv;
#pragma unroll
            for (int e = 0; e < 4; ++e) {
                float zi = acc[0][e] + bi;
                float zf = acc[1][e] + bf_;
                float zo = acc[2][e] + bo;
                float zg = acc[3][e] + bg;
                float ig = sigm(zi), fg = sigm(zf), og = sigm(zo);
                float gg = tanhft(zg);
                float cn = fg * creg[e] + ig * gg;
                creg[e] = cn;
                hv[e]   = og * tanhft(cn);
            }
            *(f32x4*)&out[(((size_t)b * HID + hch) * HDIM + r) * WDIM + w0] = hv;
            unsigned short* hb = h_bf + (size_t)(r & 1) * HBUF
                               + ((size_t)b * WDIM + w0) * HID + hch;
#pragma unroll
            for (int e = 0; e < 4; ++e) ASTORE(&hb[e * HID], f2bf(hv[e]));
        }

        if (r < HDIM - 1) {
            __syncthreads();                // drains vmcnt: h stores performed at agent scope
            if (tid == 0)
                __hip_atomic_fetch_add(&bar[(b << 6) + r], 1u,
                                       __ATOMIC_RELAXED, __HIP_MEMORY_SCOPE_AGENT);
#pragma unroll
            for (int g = 0; g < 4; ++g) acc[g] = (f32x4){0.f, 0.f, 0.f, 0.f};
            GEMM_X(lds_x[(r + 1) & 1]);    // x-part of row r+1: hides barrier skew
        }
    }
}

extern "C" void kernel_launch(void* const* d_in, const int* in_sizes, int n_in,
                              void* d_out, int out_size, void* d_ws, size_t ws_size,
                              hipStream_t stream) {
    const float* x    = (const float*)d_in[0];
    const float* W_is = (const float*)d_in[1];
    const float* b_is = (const float*)d_in[2];
    const float* W_ss = (const float*)d_in[3];
    const float* b_ss = (const float*)d_in[4];
    float* out = (float*)d_out;

    // ws: h_bf bf16[2][16*64*128] | Wpk bf16[512*640 frag-order] | bias f32[512] | bar u32[16*64]
    unsigned short* h_bf   = (unsigned short*)d_ws;                      // 524288 B
    unsigned short* Wpk    = (unsigned short*)((char*)d_ws + 524288);    // 655360 B
    float*          bias_p = (float*)((char*)d_ws + 1179648);            //   2048 B
    unsigned int*   bar    = (unsigned int*)((char*)d_ws + 1181696);     //   4096 B

    pack_kernel<<<(NTOT * KTOT + 255) / 256, 256, 0, stream>>>(
        W_is, b_is, W_ss, b_ss, Wpk, bias_p, bar);
    lstm_kernel<<<128, 256, 0, stream>>>(x, Wpk, bias_p, h_bf, bar, out);
}

// Round 4
// 386.550 us; speedup vs baseline: 2.6315x; 1.3631x over previous
//
#include <hip/hip_runtime.h>
#include <math.h>

#define CIN    128
#define HID    128
#define HDIM   64
#define WDIM   64
#define HW     4096
#define KTOT   640      // 256 x-part (2 taps x 128c) + 384 h-part (3 taps x 128c)
#define NTOT   512      // 4 gates x 128 hid
#define LDSROW 136      // shorts per A-row: 128 + 8 pad (272 B, 16B-aligned)
#define NBATCH 16
#define BFRAG  (4 * 20 * 64 * 8)   // 40960 shorts = 80 KiB per he-slice
#define HBUF   (NBATCH * WDIM * HID)   // shorts per h parity buffer

typedef short short8 __attribute__((ext_vector_type(8)));
typedef float f32x4  __attribute__((ext_vector_type(4)));
typedef unsigned int u32x4 __attribute__((ext_vector_type(4)));

#define ALOAD(p)     __hip_atomic_load((p), __ATOMIC_RELAXED, __HIP_MEMORY_SCOPE_AGENT)
#define ASTORE(p, v) __hip_atomic_store((p), (v), __ATOMIC_RELAXED, __HIP_MEMORY_SCOPE_AGENT)

__device__ __forceinline__ unsigned short f2bf(float f) {
    union { float f; unsigned int u; } v; v.f = f;
    unsigned int r = v.u + 0x7fffu + ((v.u >> 16) & 1u);   // RNE
    return (unsigned short)(r >> 16);
}
__device__ __forceinline__ float sigm(float x)  { return 1.0f / (1.0f + __expf(-x)); }
__device__ __forceinline__ float tanhft(float x){ return 2.0f / (1.0f + __expf(-2.0f * x)) - 1.0f; }

// ---------------------------------------------------------------------------
// Pack: Wpk in FRAGMENT order (see prev rounds), bias fold, zero barrier ctrs.
// ---------------------------------------------------------------------------
__global__ void pack_kernel(const float* __restrict__ W_is,
                            const float* __restrict__ b_is,
                            const float* __restrict__ W_ss,
                            const float* __restrict__ b_ss,
                            unsigned short* __restrict__ Wpk,
                            float* __restrict__ bias_p,
                            unsigned int* __restrict__ bar) {
    int idx = blockIdx.x * blockDim.x + threadIdx.x;
    if (idx < NTOT * KTOT) {
        int j    = idx & 7;
        int lane = (idx >> 3) & 63;
        int t2   = idx >> 9;            // (he*4+g)*20 + ks
        int ks   = t2 % 20;
        int gg   = t2 / 20;             // he*4 + g
        int g    = gg & 3;
        int he   = gg >> 2;
        int n = g * 128 + he * 16 + (lane & 15);
        int k = ks * 32 + (lane >> 4) * 8 + j;
        float v;
        if (k < 256) { int t = k >> 7, c = k & 127; v = W_is[((size_t)n * CIN + c) * 3 + t]; }
        else { int kk = k - 256; int t = kk >> 7, c = kk & 127; v = W_ss[((size_t)n * HID + c) * 3 + t]; }
        Wpk[idx] = f2bf(v);
    }
    if (idx < NTOT) bias_p[idx] = b_is[idx] + b_ss[idx];
    if (idx < NBATCH * HDIM) bar[idx] = 0;
}

// ---------------------------------------------------------------------------
// Persistent LSTM kernel: grid 128 = (b 0..15) x (he 0..7), 256 thr, 1 blk/CU.
// WAVE-AUTONOMOUS h-exchange:
//  - per-wave poll (64 same-addr lanes coalesce to 1 txn) on bar[b][r-1]==32
//  - per-wave STAGE_H of exactly the 18 rows the wave reads (2-row overlap
//    duplicated; identical-value LDS write races benign), lds_h double-buffered
//    by row parity -> NO cross-wave sync between stage and GEMM_H
//  - per-wave arrive: s_waitcnt vmcnt(0) (h stores visible at agent coherence
//    point; stores are sc-flagged relaxed atomics) + lane0 atomicAdd
//  - the ONE __syncthreads per row (fence for block-cooperative x staging)
//    sits AFTER the arrive -> off the inter-block critical path
// Race audit: lds_x parity vs 1 barrier/row (skew<=1 iter, disjoint parity);
// lds_h parity p rewritten 2 barriers after last read; h_bf ping-pong gated by
// bar[r]==32 which implies all reads of parity (r-1)&1 completed.
// ---------------------------------------------------------------------------
#define GEMM_X(BUF)                                                            \
    {                                                                          \
        _Pragma("unroll")                                                      \
        for (int ks = 0; ks < 8; ++ks) {                                       \
            const int t = ks >> 2, c0 = (ks & 3) * 32;                         \
            short8 a = *(const short8*)&(BUF)[(wv * 16 + t) * LDSROW + c0 + a_off]; \
            _Pragma("unroll")                                                  \
            for (int g = 0; g < 4; ++g) {                                      \
                short8 bq = *(const short8*)&lds_b[((g * 20 + ks) * 64 + lane) * 8]; \
                acc[g] = __builtin_amdgcn_mfma_f32_16x16x32_bf16(a, bq, acc[g], 0, 0, 0); \
            }                                                                  \
        }                                                                      \
    }

#define GEMM_H(LDSH)                                                           \
    {                                                                          \
        _Pragma("unroll")                                                      \
        for (int ks = 0; ks < 12; ++ks) {                                      \
            const int t = ks >> 2, c0 = (ks & 3) * 32;                         \
            short8 a = *(const short8*)&(LDSH)[(wv * 16 + t) * LDSROW + c0 + a_off]; \
            _Pragma("unroll")                                                  \
            for (int g = 0; g < 4; ++g) {                                      \
                short8 bq = *(const short8*)&lds_b[((g * 20 + 8 + ks) * 64 + lane) * 8]; \
                acc[g] = __builtin_amdgcn_mfma_f32_16x16x32_bf16(a, bq, acc[g], 0, 0, 0); \
            }                                                                  \
        }                                                                      \
    }

#define STAGE_X(ROW, BUF)                                                      \
    {                                                                          \
        const float* xrow = x + (size_t)b * (CIN * HW) + (size_t)(ROW) * WDIM; \
        _Pragma("unroll")                                                      \
        for (int p = 0; p < 16; ++p) {                                         \
            int flat = p * 256 + tid;                                          \
            int w  = flat & 63;                                                \
            int cp = flat >> 6;                                                \
            float v0 = xrow[(2 * cp    ) * HW + w];                            \
            float v1 = xrow[(2 * cp + 1) * HW + w];                            \
            ((unsigned*)(BUF))[(w + 1) * 68 + cp] =                            \
                (unsigned)f2bf(v0) | ((unsigned)f2bf(v1) << 16);               \
        }                                                                      \
    }

// per-wave coherent staged read of partner h: 18 rows (incl. halo as zeros),
// loads first (pipelined), then LDS writes. Wave-uniform control flow.
#define STAGE_H_WAVE(HB, LDSH)                                                 \
    {                                                                          \
        const unsigned* hsrc = (const unsigned*)((HB) + (size_t)b * (WDIM * HID)); \
        unsigned hv_[18];                                                      \
        _Pragma("unroll")                                                      \
        for (int i = 0; i < 18; ++i) {                                         \
            int rr = wv * 16 - 1 + i;                                          \
            hv_[i] = (rr >= 0 && rr < 64) ? ALOAD(&hsrc[rr * 64 + lane]) : 0u; \
        }                                                                      \
        _Pragma("unroll")                                                      \
        for (int i = 0; i < 18; ++i) {                                         \
            int rr = wv * 16 - 1 + i;                                          \
            ((unsigned*)(LDSH))[(rr + 1) * 68 + lane] = hv_[i];                \
        }                                                                      \
    }

__global__ __launch_bounds__(256, 1) void lstm_kernel(
        const float* __restrict__ x,
        const unsigned short* __restrict__ Wpk,
        const float* __restrict__ bias_p,
        unsigned short* h_bf,
        unsigned int* bar,
        float* __restrict__ out) {
    __shared__ __align__(16) unsigned short lds_b[BFRAG];             // 80 KiB
    __shared__ __align__(16) unsigned short lds_x[2][66 * LDSROW];    // 2 x 17.5 KiB
    __shared__ __align__(16) unsigned short lds_h[2][66 * LDSROW];    // 2 x 17.5 KiB

    const int tid  = threadIdx.x;
    const int b    = blockIdx.x & 15;      // partners share blockIdx%8 -> same XCD (perf only)
    const int he   = blockIdx.x >> 4;      // h-sixteenth (16 channels)
    const int wv   = tid >> 6;             // wave = m-tile (16 w)
    const int lane = tid & 63;
    const int quad = lane >> 4;
    const int l15  = lane & 15;

    // ---- prologue: B-slice -> LDS (contiguous, once) ----
    {
        const u32x4* src = (const u32x4*)(Wpk + (size_t)he * BFRAG);
        u32x4* dst = (u32x4*)lds_b;
#pragma unroll
        for (int p = 0; p < 20; ++p) dst[p * 256 + tid] = src[p * 256 + tid];
    }
    // x halo row 0 (w_eff = -1) stays zero; lds_h halos rewritten each stage
    if (tid < 68) {
        ((unsigned*)lds_x[0])[tid] = 0;
        ((unsigned*)lds_x[1])[tid] = 0;
        ((unsigned*)lds_h[0])[tid] = 0;
        ((unsigned*)lds_h[1])[tid] = 0;
        ((unsigned*)lds_h[0])[65 * 68 + tid] = 0;
        ((unsigned*)lds_h[1])[65 * 68 + tid] = 0;
    }
    STAGE_X(0, lds_x[0]);
    __syncthreads();

    const int hch = he * 16 + l15;
    const float bi  = bias_p[      hch];
    const float bf_ = bias_p[128 + hch];
    const float bo  = bias_p[256 + hch];
    const float bg  = bias_p[384 + hch];
    const int a_off = l15 * LDSROW + quad * 8;

    f32x4 acc[4];
#pragma unroll
    for (int g = 0; g < 4; ++g) acc[g] = (f32x4){0.f, 0.f, 0.f, 0.f};
    f32x4 creg = (f32x4){0.f, 0.f, 0.f, 0.f};

    GEMM_X(lds_x[0]);                       // x-part of row 0

    for (int r = 0; r < HDIM; ++r) {
        if (r < HDIM - 1) STAGE_X(r + 1, lds_x[(r + 1) & 1]);   // prefetch next x row

        if (r > 0) {
            const int par = (r - 1) & 1;
            // wave-level poll: 64 same-address lanes -> 1 txn per poll iter
            const unsigned* bp = &bar[(b << 6) + (r - 1)];
            while (ALOAD(bp) < 32u) { }
            STAGE_H_WAVE(h_bf + (size_t)par * HBUF, lds_h[par]);
            GEMM_H(lds_h[par]);             // wave-local: lgkm/vmcnt ordering only
        }

        // ---- LSTM epilogue: all 4 gates lane-local; c stays in registers ----
        {
            const int w0 = wv * 16 + quad * 4;
            f32x4 hv;
#pragma unroll
            for (int e = 0; e < 4; ++e) {
                float zi = acc[0][e] + bi;
                float zf = acc[1][e] + bf_;
                float zo = acc[2][e] + bo;
                float zg = acc[3][e] + bg;
                float ig = sigm(zi), fg = sigm(zf), og = sigm(zo);
                float gg = tanhft(zg);
                float cn = fg * creg[e] + ig * gg;
                creg[e] = cn;
                hv[e]   = og * tanhft(cn);
            }
            *(f32x4*)&out[(((size_t)b * HID + hch) * HDIM + r) * WDIM + w0] = hv;
            unsigned short* hb = h_bf + (size_t)(r & 1) * HBUF
                               + ((size_t)b * WDIM + w0) * HID + hch;
#pragma unroll
            for (int e = 0; e < 4; ++e) ASTORE(&hb[e * HID], f2bf(hv[e]));
        }

        if (r < HDIM - 1) {
            // per-wave publish: own stores drained at coherence point, then arrive
            asm volatile("s_waitcnt vmcnt(0) lgkmcnt(0)" ::: "memory");
            if (lane == 0)
                __hip_atomic_fetch_add(&bar[(b << 6) + r], 1u,
                                       __ATOMIC_RELAXED, __HIP_MEMORY_SCOPE_AGENT);
            __syncthreads();                // x-stage fence (off inter-block path)
#pragma unroll
            for (int g = 0; g < 4; ++g) acc[g] = (f32x4){0.f, 0.f, 0.f, 0.f};
            GEMM_X(lds_x[(r + 1) & 1]);    // x-part of row r+1: hides skew
        }
    }
}

extern "C" void kernel_launch(void* const* d_in, const int* in_sizes, int n_in,
                              void* d_out, int out_size, void* d_ws, size_t ws_size,
                              hipStream_t stream) {
    const float* x    = (const float*)d_in[0];
    const float* W_is = (const float*)d_in[1];
    const float* b_is = (const float*)d_in[2];
    const float* W_ss = (const float*)d_in[3];
    const float* b_ss = (const float*)d_in[4];
    float* out = (float*)d_out;

    // ws: h_bf bf16[2][16*64*128] | Wpk bf16[512*640 frag-order] | bias f32[512] | bar u32[16*64]
    unsigned short* h_bf   = (unsigned short*)d_ws;                      // 524288 B
    unsigned short* Wpk    = (unsigned short*)((char*)d_ws + 524288);    // 655360 B
    float*          bias_p = (float*)((char*)d_ws + 1179648);            //   2048 B
    unsigned int*   bar    = (unsigned int*)((char*)d_ws + 1181696);     //   4096 B

    pack_kernel<<<(NTOT * KTOT + 255) / 256, 256, 0, stream>>>(
        W_is, b_is, W_ss, b_ss, Wpk, bias_p, bar);
    lstm_kernel<<<128, 256, 0, stream>>>(x, Wpk, bias_p, h_bf, bar, out);
}

// Round 5
// 378.145 us; speedup vs baseline: 2.6900x; 1.0222x over previous
//
#include <hip/hip_runtime.h>
#include <math.h>

#define CIN    128
#define HID    128
#define HDIM   64
#define WDIM   64
#define HW     4096
#define KTOT   640      // 256 x-part (2 taps x 128c) + 384 h-part (3 taps x 128c)
#define NTOT   512      // 4 gates x 128 hid
#define LDSROW 136      // shorts per A-row: 128 + 8 pad (272 B, 16B-aligned)
#define NBATCH 16
#define BFRAG  (4 * 20 * 64 * 8)   // 40960 shorts = 80 KiB per he-slice
#define HBUF   (NBATCH * WDIM * HID)   // shorts per h parity buffer
#define FLAGSTRIDE 64   // u32 per batch (only first 32 used; 256 B padding)

typedef short short8 __attribute__((ext_vector_type(8)));
typedef float f32x4  __attribute__((ext_vector_type(4)));
typedef unsigned int u32x4 __attribute__((ext_vector_type(4)));

#define ALOAD(p)     __hip_atomic_load((p), __ATOMIC_RELAXED, __HIP_MEMORY_SCOPE_AGENT)
#define ASTORE(p, v) __hip_atomic_store((p), (v), __ATOMIC_RELAXED, __HIP_MEMORY_SCOPE_AGENT)

__device__ __forceinline__ unsigned short f2bf(float f) {
    union { float f; unsigned int u; } v; v.f = f;
    unsigned int r = v.u + 0x7fffu + ((v.u >> 16) & 1u);   // RNE
    return (unsigned short)(r >> 16);
}
__device__ __forceinline__ float sigm(float x)  { return 1.0f / (1.0f + __expf(-x)); }
__device__ __forceinline__ float tanhft(float x){ return 2.0f / (1.0f + __expf(-2.0f * x)) - 1.0f; }

// ---------------------------------------------------------------------------
// Pack: Wpk in FRAGMENT order (see prev rounds), bias fold, zero flag words.
// ---------------------------------------------------------------------------
__global__ void pack_kernel(const float* __restrict__ W_is,
                            const float* __restrict__ b_is,
                            const float* __restrict__ W_ss,
                            const float* __restrict__ b_ss,
                            unsigned short* __restrict__ Wpk,
                            float* __restrict__ bias_p,
                            unsigned int* __restrict__ flags) {
    int idx = blockIdx.x * blockDim.x + threadIdx.x;
    if (idx < NTOT * KTOT) {
        int j    = idx & 7;
        int lane = (idx >> 3) & 63;
        int t2   = idx >> 9;            // (he*4+g)*20 + ks
        int ks   = t2 % 20;
        int gg   = t2 / 20;             // he*4 + g
        int g    = gg & 3;
        int he   = gg >> 2;
        int n = g * 128 + he * 16 + (lane & 15);
        int k = ks * 32 + (lane >> 4) * 8 + j;
        float v;
        if (k < 256) { int t = k >> 7, c = k & 127; v = W_is[((size_t)n * CIN + c) * 3 + t]; }
        else { int kk = k - 256; int t = kk >> 7, c = kk & 127; v = W_ss[((size_t)n * HID + c) * 3 + t]; }
        Wpk[idx] = f2bf(v);
    }
    if (idx < NTOT) bias_p[idx] = b_is[idx] + b_ss[idx];
    if (idx < NBATCH * FLAGSTRIDE) flags[idx] = 0;
}

// ---------------------------------------------------------------------------
// Persistent LSTM kernel: grid 128 = (b 0..15) x (he 0..7), 256 thr, 1 blk/CU.
// WAVE-AUTONOMOUS h-exchange with PER-WAVE FLAG WORDS (no RMW counter):
//  - producer wave publishes row r by: s_waitcnt vmcnt(0) (h stores at agent
//    coherence point) then lane0 relaxed-atomic STORE flag[b][he*4+wv] = r+1.
//    32 plain stores proceed in parallel (no same-line RMW serialization).
//  - consumer poll: 64 lanes load flag[b][lane&31] (2 cache lines, one instr),
//    exit when __ballot(flag < r) == 0  -> one L3 round-trip per poll iter.
//  - per-wave STAGE_H of exactly the 18 rows the wave reads, lds_h
//    double-buffered by parity -> no cross-wave sync on the h path.
//  - ping-pong audit: flag>=r for wave W implies W finished epilogue(r-1),
//    which follows W's STAGE reads of parity (r-2)&1; producer h-writes at
//    row r happen after its own wait(all flags>=r) -> no reader still on that
//    parity. lds_x parity safe vs the single block barrier (skew <= 1 row).
// ---------------------------------------------------------------------------
#define GEMM_X(BUF)                                                            \
    {                                                                          \
        _Pragma("unroll")                                                      \
        for (int ks = 0; ks < 8; ++ks) {                                       \
            const int t = ks >> 2, c0 = (ks & 3) * 32;                         \
            short8 a = *(const short8*)&(BUF)[(wv * 16 + t) * LDSROW + c0 + a_off]; \
            _Pragma("unroll")                                                  \
            for (int g = 0; g < 4; ++g) {                                      \
                short8 bq = *(const short8*)&lds_b[((g * 20 + ks) * 64 + lane) * 8]; \
                acc[g] = __builtin_amdgcn_mfma_f32_16x16x32_bf16(a, bq, acc[g], 0, 0, 0); \
            }                                                                  \
        }                                                                      \
    }

#define GEMM_H(LDSH)                                                           \
    {                                                                          \
        _Pragma("unroll")                                                      \
        for (int ks = 0; ks < 12; ++ks) {                                      \
            const int t = ks >> 2, c0 = (ks & 3) * 32;                         \
            short8 a = *(const short8*)&(LDSH)[(wv * 16 + t) * LDSROW + c0 + a_off]; \
            _Pragma("unroll")                                                  \
            for (int g = 0; g < 4; ++g) {                                      \
                short8 bq = *(const short8*)&lds_b[((g * 20 + 8 + ks) * 64 + lane) * 8]; \
                acc[g] = __builtin_amdgcn_mfma_f32_16x16x32_bf16(a, bq, acc[g], 0, 0, 0); \
            }                                                                  \
        }                                                                      \
    }

#define STAGE_X(ROW, BUF)                                                      \
    {                                                                          \
        const float* xrow = x + (size_t)b * (CIN * HW) + (size_t)(ROW) * WDIM; \
        _Pragma("unroll")                                                      \
        for (int p = 0; p < 16; ++p) {                                         \
            int flat = p * 256 + tid;                                          \
            int w  = flat & 63;                                                \
            int cp = flat >> 6;                                                \
            float v0 = xrow[(2 * cp    ) * HW + w];                            \
            float v1 = xrow[(2 * cp + 1) * HW + w];                            \
            ((unsigned*)(BUF))[(w + 1) * 68 + cp] =                            \
                (unsigned)f2bf(v0) | ((unsigned)f2bf(v1) << 16);               \
        }                                                                      \
    }

// per-wave coherent staged read of partner h: 18 rows (incl. halo as zeros),
// loads first (pipelined, one latency), then LDS writes. Wave-uniform flow.
#define STAGE_H_WAVE(HB, LDSH)                                                 \
    {                                                                          \
        const unsigned* hsrc = (const unsigned*)((HB) + (size_t)b * (WDIM * HID)); \
        unsigned hv_[18];                                                      \
        _Pragma("unroll")                                                      \
        for (int i = 0; i < 18; ++i) {                                         \
            int rr = wv * 16 - 1 + i;                                          \
            hv_[i] = (rr >= 0 && rr < 64) ? ALOAD(&hsrc[rr * 64 + lane]) : 0u; \
        }                                                                      \
        _Pragma("unroll")                                                      \
        for (int i = 0; i < 18; ++i) {                                         \
            int rr = wv * 16 - 1 + i;                                          \
            ((unsigned*)(LDSH))[(rr + 1) * 68 + lane] = hv_[i];                \
        }                                                                      \
    }

__global__ __launch_bounds__(256, 1) void lstm_kernel(
        const float* __restrict__ x,
        const unsigned short* __restrict__ Wpk,
        const float* __restrict__ bias_p,
        unsigned short* h_bf,
        unsigned int* flags,
        float* __restrict__ out) {
    __shared__ __align__(16) unsigned short lds_b[BFRAG];             // 80 KiB
    __shared__ __align__(16) unsigned short lds_x[2][66 * LDSROW];    // 2 x 17.5 KiB
    __shared__ __align__(16) unsigned short lds_h[2][66 * LDSROW];    // 2 x 17.5 KiB

    const int tid  = threadIdx.x;
    const int b    = blockIdx.x & 15;      // partners share blockIdx%8 -> same XCD (perf only)
    const int he   = blockIdx.x >> 4;      // h-sixteenth (16 channels)
    const int wv   = tid >> 6;             // wave = m-tile (16 w)
    const int lane = tid & 63;
    const int quad = lane >> 4;
    const int l15  = lane & 15;

    unsigned int* bflag = flags + b * FLAGSTRIDE;   // 32 live flags, 2 lines

    // ---- prologue: B-slice -> LDS (contiguous, once) ----
    {
        const u32x4* src = (const u32x4*)(Wpk + (size_t)he * BFRAG);
        u32x4* dst = (u32x4*)lds_b;
#pragma unroll
        for (int p = 0; p < 20; ++p) dst[p * 256 + tid] = src[p * 256 + tid];
    }
    // x halo row 0 (w_eff = -1) stays zero; lds_h halos rewritten each stage
    if (tid < 68) {
        ((unsigned*)lds_x[0])[tid] = 0;
        ((unsigned*)lds_x[1])[tid] = 0;
        ((unsigned*)lds_h[0])[tid] = 0;
        ((unsigned*)lds_h[1])[tid] = 0;
        ((unsigned*)lds_h[0])[65 * 68 + tid] = 0;
        ((unsigned*)lds_h[1])[65 * 68 + tid] = 0;
    }
    STAGE_X(0, lds_x[0]);
    __syncthreads();

    const int hch = he * 16 + l15;
    const float bi  = bias_p[      hch];
    const float bf_ = bias_p[128 + hch];
    const float bo  = bias_p[256 + hch];
    const float bg  = bias_p[384 + hch];
    const int a_off = l15 * LDSROW + quad * 8;

    f32x4 acc[4];
#pragma unroll
    for (int g = 0; g < 4; ++g) acc[g] = (f32x4){0.f, 0.f, 0.f, 0.f};
    f32x4 creg = (f32x4){0.f, 0.f, 0.f, 0.f};

    GEMM_X(lds_x[0]);                       // x-part of row 0

    for (int r = 0; r < HDIM; ++r) {
        if (r < HDIM - 1) STAGE_X(r + 1, lds_x[(r + 1) & 1]);   // prefetch next x row

        if (r > 0) {
            const int par = (r - 1) & 1;
            // flag poll: 64 lanes cover 32 flags (2 lines) -> 1 txn/iter
            const unsigned* fp = &bflag[lane & 31];
            const unsigned want = (unsigned)r;
            while (__ballot(ALOAD(fp) < want) != 0ull) { }
            STAGE_H_WAVE(h_bf + (size_t)par * HBUF, lds_h[par]);
            GEMM_H(lds_h[par]);             // wave-local: lgkm/vmcnt ordering only
        }

        // ---- LSTM epilogue: all 4 gates lane-local; c stays in registers ----
        {
            const int w0 = wv * 16 + quad * 4;
            f32x4 hv;
#pragma unroll
            for (int e = 0; e < 4; ++e) {
                float zi = acc[0][e] + bi;
                float zf = acc[1][e] + bf_;
                float zo = acc[2][e] + bo;
                float zg = acc[3][e] + bg;
                float ig = sigm(zi), fg = sigm(zf), og = sigm(zo);
                float gg = tanhft(zg);
                float cn = fg * creg[e] + ig * gg;
                creg[e] = cn;
                hv[e]   = og * tanhft(cn);
            }
            *(f32x4*)&out[(((size_t)b * HID + hch) * HDIM + r) * WDIM + w0] = hv;
            unsigned short* hb = h_bf + (size_t)(r & 1) * HBUF
                               + ((size_t)b * WDIM + w0) * HID + hch;
#pragma unroll
            for (int e = 0; e < 4; ++e) ASTORE(&hb[e * HID], f2bf(hv[e]));
        }

        if (r < HDIM - 1) {
            // per-wave publish: drain own stores to coherence point, then flag
            asm volatile("s_waitcnt vmcnt(0) lgkmcnt(0)" ::: "memory");
            if (lane == 0) ASTORE(&bflag[(he << 2) + wv], (unsigned)(r + 1));
            __syncthreads();                // x-stage fence (off inter-block path)
#pragma unroll
            for (int g = 0; g < 4; ++g) acc[g] = (f32x4){0.f, 0.f, 0.f, 0.f};
            GEMM_X(lds_x[(r + 1) & 1]);    // x-part of row r+1: hides skew
        }
    }
}

extern "C" void kernel_launch(void* const* d_in, const int* in_sizes, int n_in,
                              void* d_out, int out_size, void* d_ws, size_t ws_size,
                              hipStream_t stream) {
    const float* x    = (const float*)d_in[0];
    const float* W_is = (const float*)d_in[1];
    const float* b_is = (const float*)d_in[2];
    const float* W_ss = (const float*)d_in[3];
    const float* b_ss = (const float*)d_in[4];
    float* out = (float*)d_out;

    // ws: h_bf bf16[2][16*64*128] | Wpk bf16[512*640 frag-order] | bias f32[512] | flags u32[16*64]
    unsigned short* h_bf   = (unsigned short*)d_ws;                      // 524288 B
    unsigned short* Wpk    = (unsigned short*)((char*)d_ws + 524288);    // 655360 B
    float*          bias_p = (float*)((char*)d_ws + 1179648);            //   2048 B
    unsigned int*   flags  = (unsigned int*)((char*)d_ws + 1181696);     //   4096 B

    pack_kernel<<<(NTOT * KTOT + 255) / 256, 256, 0, stream>>>(
        W_is, b_is, W_ss, b_ss, Wpk, bias_p, flags);
    lstm_kernel<<<128, 256, 0, stream>>>(x, Wpk, bias_p, h_bf, flags, out);
}